// Round 10
// baseline (287.981 us; speedup 1.0000x reference)
//
#include <hip/hip_runtime.h>
#include <math.h>

#define T_TOKENS 32768
#define HIDDEN   4096
#define NEXP     128
#define TM       64
#define BK       32
#define NSTAGE   (HIDDEN / BK)            // 128

// LDS: A double-buffer only (B lives in registers now).
// [Abuf0 12KB][Abuf1 12KB] = 24 KB; epilogue sc overlay needs 33 KB -> size to it.
#define A_BUF_SH      6144                // shorts per A buffer (3 planes x 2048)
#define A_PLANE_SH    2048
#define SC_STRIDE     129
#define LDS_SHORTS    16512               // 33024 B = [64][129] f32 overlay
#define B_CHUNK_SH    12288               // shorts per stage in w image
#define WS_BYTES ((size_t)NSTAGE * B_CHUNK_SH * 2)  // 3 MiB

typedef short bf16x8 __attribute__((ext_vector_type(8)));
typedef short bf16x4 __attribute__((ext_vector_type(4)));
typedef float f32x4  __attribute__((ext_vector_type(4)));

__device__ __forceinline__ unsigned short f2bf(float f) {
    unsigned u = __float_as_uint(f);
    u += 0x7FFF + ((u >> 16) & 1);          // round-to-nearest-even
    return (unsigned short)(u >> 16);
}
__device__ __forceinline__ float bf2f(unsigned short h) {
    return __uint_as_float(((unsigned)h) << 16);
}
// 3-term bf16 cascade: x = b0 + b1 + b2 + delta, |delta| <= 2^-27 |x|
__device__ __forceinline__ void split3(float x, unsigned short& b0,
                                       unsigned short& b1, unsigned short& b2) {
    b0 = f2bf(x);
    float r1 = x - bf2f(b0);                // exact (Sterbenz)
    b1 = f2bf(r1);
    float r2 = r1 - bf2f(b1);               // exact
    b2 = f2bf(r2);
}

// ---- kernel 1: split w into 3 bf16 planes, fragment-major (IDENTICAL image
// to rounds 5-9): stage s, plane p, tile t, lane l holds
// w[t*16+(l&15)][s*32+(l>>4)*8+j] at ws16[((s*24 + p*8 + t)*64 + l)*8].
// Main kernel now reads fragments STRAIGHT from this image into VGPRs.
__global__ __launch_bounds__(256) void presplit_w(
    const float* __restrict__ w, short* __restrict__ ws16)
{
    const int g = blockIdx.x * 256 + threadIdx.x;    // 65536 total
    const int l = g & 63;
    const int t = (g >> 6) & 7;
    const int s = g >> 9;                            // 0..127
    const int e  = t * 16 + (l & 15);
    const int kb = s * BK + ((l >> 4) & 3) * 8;
    const float* src = w + (size_t)e * HIDDEN + kb;
    float4 v0 = *(const float4*)(src);
    float4 v1 = *(const float4*)(src + 4);
    float vv[8] = {v0.x, v0.y, v0.z, v0.w, v1.x, v1.y, v1.z, v1.w};
    unsigned short h0[8], h1[8], h2[8];
#pragma unroll
    for (int j = 0; j < 8; ++j) split3(vv[j], h0[j], h1[j], h2[j]);
    const size_t base = ((size_t)s * 24 + t) * 64 + l;
    bf16x8 o0 = {(short)h0[0],(short)h0[1],(short)h0[2],(short)h0[3],
                 (short)h0[4],(short)h0[5],(short)h0[6],(short)h0[7]};
    bf16x8 o1 = {(short)h1[0],(short)h1[1],(short)h1[2],(short)h1[3],
                 (short)h1[4],(short)h1[5],(short)h1[6],(short)h1[7]};
    bf16x8 o2 = {(short)h2[0],(short)h2[1],(short)h2[2],(short)h2[3],
                 (short)h2[4],(short)h2[5],(short)h2[6],(short)h2[7]};
    *(bf16x8*)(ws16 + (base + 0 * 8 * 64) * 8) = o0;
    *(bf16x8*)(ws16 + (base + 1 * 8 * 64) * 8) = o1;
    *(bf16x8*)(ws16 + (base + 2 * 8 * 64) * 8) = o2;
}

// 512 threads = 8 waves; wave owns 32 tok x 32 exp (2x2 of 16x16 tiles).
// B fragments: global->VGPR (per-wave private, L2-served, never barriered).
// A: split->LDS double-buffer; the ONLY cross-wave handoff -> raw s_barrier
// with lgkmcnt(0) only. No vmcnt drain anywhere in the main loop: the x
// prefetch (2 stages deep) and B loads stay in flight across barriers.
__global__ __launch_bounds__(512, 4) void glm4_router_mfma(
    const float* __restrict__ x, const short* __restrict__ wsplit,
    const float* __restrict__ bias, float* __restrict__ out)
{
    __shared__ __align__(16) short lds[LDS_SHORTS];

    const int tid  = threadIdx.x;
    const int wid  = tid >> 6;
    const int lane = tid & 63;
    const int rt_base = (wid & 1) * 2;      // row-tile base: 0 or 2
    const int ct_base = (wid >> 1) * 2;     // col-tile base: 0,2,4,6
    const int tok_base = blockIdx.x * TM;

    // A staging: thread tid b64-writes shorts [tid*4..tid*4+3] of each plane
    // (contiguous across the wave). Fragment image needs this thread to hold
    // x[row][k] with t=tid>>7, l=(tid>>1)&63, j4=(tid&1)*4:
    // row = t*16+(l&15), k = s*32 + ((l>>4)&3)*8 + j4.
    const int al = (tid >> 1) & 63;
    const int at = tid >> 7;
    const int arow = at * 16 + (al & 15);
    const int akoff = ((al >> 4) & 3) * 8 + (tid & 1) * 4;
    const float* xsrc = x + (size_t)(tok_base + arow) * HIDDEN + akoff;
    const int awr = tid * 4;                // shorts, within a plane

    // B fragment base for this wave (shorts): tiles ct_base, ct_base+1
    const short* wfrag = wsplit + (size_t)lane * 8;

    f32x4 acc[2][2];        // all 6 split-products, zeroed every K=128
    double accd[2][2][4];   // fp64 running sum
#pragma unroll
    for (int r = 0; r < 2; ++r)
#pragma unroll
        for (int c = 0; c < 2; ++c) {
            acc[r][c] = (f32x4){0.f, 0.f, 0.f, 0.f};
#pragma unroll
            for (int v = 0; v < 4; ++v) accd[r][c][v] = 0.0;
        }

#define SPLIT_A(XV, BUF) do {                                                  \
    unsigned short h0_[4], h1_[4], h2_[4];                                     \
    split3((XV).x, h0_[0], h1_[0], h2_[0]);                                    \
    split3((XV).y, h0_[1], h1_[1], h2_[1]);                                    \
    split3((XV).z, h0_[2], h1_[2], h2_[2]);                                    \
    split3((XV).w, h0_[3], h1_[3], h2_[3]);                                    \
    short* ab_ = &lds[(BUF) * A_BUF_SH + awr];                                 \
    *(bf16x4*)(ab_ + 0 * A_PLANE_SH) =                                         \
        (bf16x4){(short)h0_[0], (short)h0_[1], (short)h0_[2], (short)h0_[3]};  \
    *(bf16x4*)(ab_ + 1 * A_PLANE_SH) =                                         \
        (bf16x4){(short)h1_[0], (short)h1_[1], (short)h1_[2], (short)h1_[3]};  \
    *(bf16x4*)(ab_ + 2 * A_PLANE_SH) =                                         \
        (bf16x4){(short)h2_[0], (short)h2_[1], (short)h2_[2], (short)h2_[3]};  \
} while (0)

    // barrier pair: drain LDS ops, rendezvous, pin against reordering
#define A_BARRIER() do {                                                       \
    asm volatile("s_waitcnt lgkmcnt(0)" ::: "memory");                         \
    __builtin_amdgcn_s_barrier();                                              \
    __builtin_amdgcn_sched_barrier(0);                                         \
} while (0)

    // body(s): load B(s) frags global->reg, prefetch x[s+2], split x[s+1]
    // into Abuf^1, ds_read A(s) from Abuf, 24 MFMA, fold, A_BARRIER.
#define BODY(S, BUF, XC, XL) do {                                              \
    bf16x8 Bf[3][2];                                                           \
    _Pragma("unroll")                                                          \
    for (int p = 0; p < 3; ++p) {                                              \
        _Pragma("unroll")                                                      \
        for (int c = 0; c < 2; ++c)                                            \
            Bf[p][c] = *(const bf16x8*)(                                       \
                wfrag + ((size_t)(S) * 24 + p * 8 + ct_base + c) * 512);       \
    }                                                                          \
    {                                                                          \
        int s2_ = (S) + 2; if (s2_ > NSTAGE - 1) s2_ = NSTAGE - 1;             \
        XL = *(const float4*)(xsrc + (size_t)s2_ * BK);                        \
    }                                                                          \
    SPLIT_A(XC, (BUF) ^ 1);                                                    \
    bf16x8 Af[3][2];                                                           \
    _Pragma("unroll")                                                          \
    for (int p = 0; p < 3; ++p)                                                \
        _Pragma("unroll")                                                      \
        for (int r = 0; r < 2; ++r)                                            \
            Af[p][r] = *(const bf16x8*)(&lds[(BUF) * A_BUF_SH + p * A_PLANE_SH \
                                             + ((rt_base + r) * 64 + lane) * 8]); \
    _Pragma("unroll")                                                          \
    for (int r = 0; r < 2; ++r) {                                              \
        _Pragma("unroll")                                                      \
        for (int c = 0; c < 2; ++c) {                                          \
            acc[r][c] = __builtin_amdgcn_mfma_f32_16x16x32_bf16(Af[0][r], Bf[0][c], acc[r][c], 0, 0, 0); \
            acc[r][c] = __builtin_amdgcn_mfma_f32_16x16x32_bf16(Af[0][r], Bf[1][c], acc[r][c], 0, 0, 0); \
            acc[r][c] = __builtin_amdgcn_mfma_f32_16x16x32_bf16(Af[1][r], Bf[0][c], acc[r][c], 0, 0, 0); \
            acc[r][c] = __builtin_amdgcn_mfma_f32_16x16x32_bf16(Af[0][r], Bf[2][c], acc[r][c], 0, 0, 0); \
            acc[r][c] = __builtin_amdgcn_mfma_f32_16x16x32_bf16(Af[2][r], Bf[0][c], acc[r][c], 0, 0, 0); \
            acc[r][c] = __builtin_amdgcn_mfma_f32_16x16x32_bf16(Af[1][r], Bf[1][c], acc[r][c], 0, 0, 0); \
        }                                                                      \
    }                                                                          \
    if (((S) & 3) == 3) {                                                      \
        _Pragma("unroll")                                                      \
        for (int r = 0; r < 2; ++r)                                            \
            _Pragma("unroll")                                                  \
            for (int c = 0; c < 2; ++c) {                                      \
                _Pragma("unroll")                                              \
                for (int v = 0; v < 4; ++v) accd[r][c][v] += (double)acc[r][c][v]; \
                acc[r][c] = (f32x4){0.f, 0.f, 0.f, 0.f};                       \
            }                                                                  \
    }                                                                          \
    A_BARRIER();                                                               \
} while (0)

    // prologue: split x[0] into Abuf0, prefetch x[1]
    float4 xA, xB;
    {
        float4 x0v = *(const float4*)(xsrc);
        xA = *(const float4*)(xsrc + BK);   // x[1]
        SPLIT_A(x0v, 1);                    // BUF^1 with BUF=... write buf... 
    }
    // NOTE: SPLIT_A(x0v, 1) wrote buf1?? -> stage 0 must be in buf0.
    // (kept explicit below: we wrote buf'1' meaning index 1; fix by writing 0)
    // -- corrected prologue:
    {
        // overwrite properly: stage 0 lives in buf0
        float4 x0v = *(const float4*)(xsrc);
        SPLIT_A(x0v, 0);
    }
    A_BARRIER();

    for (int s = 0; s < NSTAGE - 2; s += 2) {
        BODY(s, 0, xA, xB);
        BODY(s + 1, 1, xB, xA);
    }
    BODY(NSTAGE - 2, 0, xA, xB);

    // tail: stage 127 from Abuf1, B loaded inline, no barrier/staging
    {
        const int S = NSTAGE - 1;
        bf16x8 Bf[3][2];
#pragma unroll
        for (int p = 0; p < 3; ++p)
#pragma unroll
            for (int c = 0; c < 2; ++c)
                Bf[p][c] = *(const bf16x8*)(
                    wfrag + ((size_t)S * 24 + p * 8 + ct_base + c) * 512);
        bf16x8 Af[3][2];
#pragma unroll
        for (int p = 0; p < 3; ++p)
#pragma unroll
            for (int r = 0; r < 2; ++r)
                Af[p][r] = *(const bf16x8*)(&lds[1 * A_BUF_SH + p * A_PLANE_SH
                                                 + ((rt_base + r) * 64 + lane) * 8]);
#pragma unroll
        for (int r = 0; r < 2; ++r)
#pragma unroll
            for (int c = 0; c < 2; ++c) {
                acc[r][c] = __builtin_amdgcn_mfma_f32_16x16x32_bf16(Af[0][r], Bf[0][c], acc[r][c], 0, 0, 0);
                acc[r][c] = __builtin_amdgcn_mfma_f32_16x16x32_bf16(Af[0][r], Bf[1][c], acc[r][c], 0, 0, 0);
                acc[r][c] = __builtin_amdgcn_mfma_f32_16x16x32_bf16(Af[1][r], Bf[0][c], acc[r][c], 0, 0, 0);
                acc[r][c] = __builtin_amdgcn_mfma_f32_16x16x32_bf16(Af[0][r], Bf[2][c], acc[r][c], 0, 0, 0);
                acc[r][c] = __builtin_amdgcn_mfma_f32_16x16x32_bf16(Af[2][r], Bf[0][c], acc[r][c], 0, 0, 0);
                acc[r][c] = __builtin_amdgcn_mfma_f32_16x16x32_bf16(Af[1][r], Bf[1][c], acc[r][c], 0, 0, 0);
            }
        // final fold (S=127 -> (S&3)==3)
#pragma unroll
        for (int r = 0; r < 2; ++r)
#pragma unroll
            for (int c = 0; c < 2; ++c)
#pragma unroll
                for (int v = 0; v < 4; ++v) accd[r][c][v] += (double)acc[r][c][v];
    }

    // ---- epilogue: logits -> biased scores into LDS overlay (fp32) ----
    __syncthreads();
    float* sc = (float*)lds;                       // [64][129] = 33 KB
#pragma unroll
    for (int r = 0; r < 2; ++r)
#pragma unroll
        for (int c = 0; c < 2; ++c) {
#pragma unroll
            for (int v = 0; v < 4; ++v) {
                const int tokl = (rt_base + r) * 16 + (lane >> 4) * 4 + v;
                const int e    = (ct_base + c) * 16 + (lane & 15);
                const float lg = (float)accd[r][c][v];
                const float sg = (float)(1.0 / (1.0 + exp(-(double)lg)));
                sc[tokl * SC_STRIDE + e] = sg + bias[e];
            }
        }
    __syncthreads();

    // ---- routing: one lane per token (wave 0) — verified logic ----
    if (tid < TM) {
        const float* scp = sc + tid * SC_STRIDE;

        float gsc[8];
#pragma unroll
        for (int g = 0; g < 8; ++g) {
            float m1 = -1e30f, m2 = -1e30f;
#pragma unroll
            for (int j = 0; j < 16; ++j) {
                const float v = scp[g * 16 + j];
                if (v > m1) { m2 = m1; m1 = v; }
                else if (v > m2) { m2 = v; }
            }
            gsc[g] = m1 + m2;
        }

        unsigned gmask = 0;
#pragma unroll
        for (int p = 0; p < 4; ++p) {
            float best = -1e30f; int bi = 0;
#pragma unroll
            for (int g = 0; g < 8; ++g) {
                const bool taken = (gmask >> g) & 1u;
                if (!taken && gsc[g] > best) { best = gsc[g]; bi = g; }
            }
            gmask |= 1u << bi;
        }

        unsigned long long chosen0 = 0ull, chosen1 = 0ull;
        int   idxs[8];
        float wts[8];
#pragma unroll
        for (int p = 0; p < 8; ++p) {
            float best = -1e30f; int bi = 0;
            for (int e = 0; e < NEXP; ++e) {
                const bool sel = (gmask >> (e >> 4)) & 1u;
                const float v = sel ? scp[e] : 0.0f;
                const bool ch = (e < 64) ? ((chosen0 >> e) & 1ull)
                                         : ((chosen1 >> (e - 64)) & 1ull);
                if (!ch && v > best) { best = v; bi = e; }
            }
            if (bi < 64) chosen0 |= 1ull << bi; else chosen1 |= 1ull << (bi - 64);
            idxs[p] = bi;
            wts[p] = scp[bi] - bias[bi];   // raw sigmoid, ~1e-7 error
        }

        float denom = 0.0f;
#pragma unroll
        for (int p = 0; p < 8; ++p) denom += wts[p];
        denom += 1e-20f;

        const size_t row = (size_t)(tok_base + tid) * 8;
        float* outI = out;
        float* outW = out + (size_t)T_TOKENS * 8;
#pragma unroll
        for (int p = 0; p < 8; ++p) {
            outI[row + p] = (float)idxs[p];
            outW[row + p] = wts[p] / denom;
        }
    }
}

extern "C" void kernel_launch(void* const* d_in, const int* in_sizes, int n_in,
                              void* d_out, int out_size, void* d_ws, size_t ws_size,
                              hipStream_t stream) {
    const float* x    = (const float*)d_in[0];  // [32768, 4096]
    const float* w    = (const float*)d_in[1];  // [128, 4096]
    const float* bias = (const float*)d_in[2];  // [128]
    float* out = (float*)d_out;                 // [idx-as-float | weights]
    short* ws16 = (short*)d_ws;                 // 3 MiB pre-split w image

    presplit_w<<<dim3(NSTAGE * 8 * 64 / 256), 256, 0, stream>>>(w, ws16);
    glm4_router_mfma<<<dim3(T_TOKENS / TM), 512, 0, stream>>>(x, ws16, bias, out);
}